// Round 6
// baseline (123.981 us; speedup 1.0000x reference)
//
#include <hip/hip_runtime.h>

// Modulated deformable conv2d, fp32 in/out, bf16 MFMA core.
// B=4, C=64, H=W=128, O=64, K=3x3, stride=1, pad=1, dil=1, og=1, groups=1.
//
// Round 6: kill the per-tap LDS round-trip. Key observation: the A-operand
// fragment of mfma_f32_16x16x32_bf16 is A[m=lane&15][k=quad*8+j] -- lane l
// needs 16 channels of ONE pixel. So let lane l bilinear-sample pixel
// m0+(l&15), channels q*32+quad*8..+8, directly into the A-fragment
// registers. No LDS tile, no barriers, waves fully independent.
// (Round-5 evidence: LDS version passed at absmax 1.6e-2; ~49 us of dur_us
// is the harness's 256 MiB d_ws re-poison fill -- irreducible floor.)
// Fragment layouts (m89/m120-verified): A[m=lane&15][k=quad*8+j],
// B[k=quad*8+j][n=lane&15], D[row=quad*4+reg][col=lane&15].

#define BB 4
#define CC 64
#define HH 128
#define WW 128
#define OO 64
#define KHW 3
#define KK 9
#define HW (HH * WW)

typedef __bf16 bf16_t;
typedef bf16_t bf16x8 __attribute__((ext_vector_type(8)));
typedef float f32x4 __attribute__((ext_vector_type(4)));

// ---- x (NCHW fp32) -> xt (NHWC bf16), LDS-tiled transpose ----
__global__ __launch_bounds__(256) void nhwc_kernel(const float* __restrict__ x,
                                                   bf16_t* __restrict__ xt) {
    __shared__ float tile[64 * 65];
    const int t  = threadIdx.x;
    const int b  = blockIdx.x >> 8;
    const int p0 = (blockIdx.x & 255) << 6;
#pragma unroll
    for (int i = 0; i < 16; ++i) {
        int c = i * 4 + (t >> 6);
        int p = t & 63;
        tile[c * 65 + p] = x[(b * CC + c) * HW + p0 + p];  // coalesced read
    }
    __syncthreads();
#pragma unroll
    for (int i = 0; i < 16; ++i) {
        int p = i * 4 + (t >> 6);
        int c = t & 63;
        xt[(size_t)((b * HW) + p0 + p) * CC + c] = (bf16_t)tile[c * 65 + p];
    }
}

// ---- weight [O][C][3][3] fp32 -> B-fragment order bf16 ----
// wf element index: ((tap*2+q)*4+nt)*64*8 + lane*8 + j
//   holds W[o = nt*16 + (lane&15)][c = q*32 + (lane>>4)*8 + j][tap]
__global__ void wfrag_kernel(const float* __restrict__ w,
                             bf16_t* __restrict__ wf) {
    int i = blockIdx.x * blockDim.x + threadIdx.x;
    if (i >= OO * CC * KK) return;
    int j    = i & 7;
    int lane = (i >> 3) & 63;
    int nt   = (i >> 9) & 3;
    int q    = (i >> 11) & 1;
    int k    = i >> 12;
    int o = nt * 16 + (lane & 15);
    int c = q * 32 + ((lane >> 4) << 3) + j;
    wf[i] = (bf16_t)w[(o * CC + c) * KK + k];
}

__global__ __launch_bounds__(256, 2) void deform_conv_mfma(
    const bf16_t* __restrict__ xt, const float* __restrict__ offset,
    const float* __restrict__ mask, const bf16x8* __restrict__ wf,
    const float* __restrict__ bias, float* __restrict__ out) {
    const int t    = threadIdx.x;
    const int b    = blockIdx.x >> 8;
    const int p0   = (blockIdx.x & 255) << 6;  // block's 64-pixel group
    const int lane = t & 63;
    const int wv   = t >> 6;
    const int m0   = wv << 4;                  // wave's 16-pixel strip
    const int col  = lane & 15;
    const int quad = lane >> 4;

    // This lane samples pixel (m0+col), channels q*32 + quad*8 .. +8 --
    // exactly its A-fragment slots.
    const int rem = p0 + m0 + col;
    const int ho  = rem >> 7;
    const int wo  = rem & (WW - 1);
    const int chq = quad << 3;                 // quad's 8-channel base

    const bf16_t* xb = xt + (size_t)b * HW * CC;

    f32x4 acc[4];
#pragma unroll
    for (int nt = 0; nt < 4; ++nt) acc[nt] = (f32x4){0.f, 0.f, 0.f, 0.f};

    for (int k = 0; k < KK; ++k) {
        // ---- per-tap sampling setup (same pixel for all 4 quads) ----
        float offy = offset[((b * (2 * KK) + 2 * k) * HW) + rem];
        float offx = offset[((b * (2 * KK) + 2 * k + 1) * HW) + rem];
        float mm   = mask[((b * KK + k) * HW) + rem];
        float py = offy + (float)(k / KHW) + (float)(ho - 1);
        float px = offx + (float)(k % KHW) + (float)(wo - 1);
        float fy0 = floorf(py), fx0 = floorf(px);
        float ly = py - fy0, lx = px - fx0;
        int y0 = (int)fy0, x0 = (int)fx0;
        int y1 = y0 + 1, x1 = x0 + 1;
        bool vy0 = (y0 >= 0) && (y0 < HH);
        bool vy1 = (y1 >= 0) && (y1 < HH);
        bool vx0 = (x0 >= 0) && (x0 < WW);
        bool vx1 = (x1 >= 0) && (x1 < WW);
        int cy0 = min(max(y0, 0), HH - 1), cy1 = min(max(y1, 0), HH - 1);
        int cx0 = min(max(x0, 0), WW - 1), cx1 = min(max(x1, 0), WW - 1);
        float w0 = (vy0 && vx0) ? mm * (1.0f - ly) * (1.0f - lx) : 0.0f;
        float w1 = (vy0 && vx1) ? mm * (1.0f - ly) * lx : 0.0f;
        float w2 = (vy1 && vx0) ? mm * ly * (1.0f - lx) : 0.0f;
        float w3 = (vy1 && vx1) ? mm * ly * lx : 0.0f;

        const bf16_t* c00 = xb + (cy0 * WW + cx0) * CC + chq;
        const bf16_t* c01 = xb + (cy0 * WW + cx1) * CC + chq;
        const bf16_t* c10 = xb + (cy1 * WW + cx0) * CC + chq;
        const bf16_t* c11 = xb + (cy1 * WW + cx1) * CC + chq;

        // Load all 8 corner vectors (q=0: +0, q=1: +32 channels) up front.
        bf16x8 a00 = *(const bf16x8*)(c00);
        bf16x8 a01 = *(const bf16x8*)(c01);
        bf16x8 a02 = *(const bf16x8*)(c10);
        bf16x8 a03 = *(const bf16x8*)(c11);
        bf16x8 a10 = *(const bf16x8*)(c00 + 32);
        bf16x8 a11 = *(const bf16x8*)(c01 + 32);
        bf16x8 a12 = *(const bf16x8*)(c10 + 32);
        bf16x8 a13 = *(const bf16x8*)(c11 + 32);

        bf16x8 af0, af1;
#pragma unroll
        for (int i = 0; i < 8; ++i) {
            float v = w0 * (float)a00[i] + w1 * (float)a01[i] +
                      w2 * (float)a02[i] + w3 * (float)a03[i];
            af0[i] = (bf16_t)v;
        }
#pragma unroll
        for (int i = 0; i < 8; ++i) {
            float v = w0 * (float)a10[i] + w1 * (float)a11[i] +
                      w2 * (float)a12[i] + w3 * (float)a13[i];
            af1[i] = (bf16_t)v;
        }

        // ---- MFMA: 2 K-chunks x 4 N-tiles, B frags from global (L2) ----
        const bf16x8* wk = wf + (size_t)(k * 8) * 64;
#pragma unroll
        for (int nt = 0; nt < 4; ++nt) {
            bf16x8 b0 = wk[nt * 64 + lane];
            acc[nt] = __builtin_amdgcn_mfma_f32_16x16x32_bf16(af0, b0, acc[nt],
                                                              0, 0, 0);
        }
#pragma unroll
        for (int nt = 0; nt < 4; ++nt) {
            bf16x8 b1 = wk[(4 + nt) * 64 + lane];
            acc[nt] = __builtin_amdgcn_mfma_f32_16x16x32_bf16(af1, b1, acc[nt],
                                                              0, 0, 0);
        }
    }

    // ---- epilogue: D[row=quad*4+reg][col]; row -> pixel, col -> output ----
#pragma unroll
    for (int nt = 0; nt < 4; ++nt) {
        int o = nt * 16 + col;
        float bv = bias[o];
        f32x4 r = acc[nt];
        r.x += bv; r.y += bv; r.z += bv; r.w += bv;
        float* dst = out + (size_t)(b * OO + o) * HW + p0 + m0 + quad * 4;
        *(f32x4*)dst = r;  // 4 consecutive pixels, 16B aligned
    }
}

extern "C" void kernel_launch(void* const* d_in, const int* in_sizes, int n_in,
                              void* d_out, int out_size, void* d_ws,
                              size_t ws_size, hipStream_t stream) {
    const float* x      = (const float*)d_in[0];
    const float* offset = (const float*)d_in[1];
    const float* mask   = (const float*)d_in[2];
    const float* weight = (const float*)d_in[3];
    const float* bias   = (const float*)d_in[4];
    float* out = (float*)d_out;

    bf16_t* xt  = (bf16_t*)d_ws;                      // 4*16384*64*2 = 8 MB
    bf16_t* wfr = (bf16_t*)((char*)d_ws + (size_t)BB * HW * CC * 2);  // 72 KB

    nhwc_kernel<<<BB * (HW / 64), 256, 0, stream>>>(x, xt);

    int nw = OO * CC * KK;  // 36864
    wfrag_kernel<<<(nw + 255) / 256, 256, 0, stream>>>(weight, wfr);

    deform_conv_mfma<<<BB * (HW / 64), 256, 0, stream>>>(
        xt, offset, mask, (const bf16x8*)wfr, bias, out);
}

// Round 7
// 123.419 us; speedup vs baseline: 1.0046x; 1.0046x over previous
//
#include <hip/hip_runtime.h>

// Modulated deformable conv2d, fp32 in/out, bf16 MFMA core.
// B=4, C=64, H=W=128, O=64, K=3x3, stride=1, pad=1, dil=1, og=1, groups=1.
//
// Round 7: the round-6 kernel was latency-bound at 2.75 waves/SIMD
// (MfmaUtil 3.5%, VALUBusy 21%, grid-capped at 4 waves/SIMD). M-dim is
// exhausted (4096 strips), so split K: each block = 2 pixel-strips x
// 2 channel-halves (4 waves); per wave per tap: 4 corner loads (32 ch),
// 1 bilinear A-frag, 4 MFMAs. Grid 2048 blocks -> 8192 waves = 8/SIMD
// ceiling; live state ~55 VGPR so 6-8 waves/SIMD fit. One LDS reduction
// (8 KB, f32x4 -> conflict-free) at the end combines halves; next-tap
// offset/mask explicitly prefetched.
// Fragment layouts (m89/m120-verified): A[m=lane&15][k=quad*8+j],
// B[k=quad*8+j][n=lane&15], D[row=quad*4+reg][col=lane&15].

#define BB 4
#define CC 64
#define HH 128
#define WW 128
#define OO 64
#define KHW 3
#define KK 9
#define HW (HH * WW)

typedef __bf16 bf16_t;
typedef bf16_t bf16x8 __attribute__((ext_vector_type(8)));
typedef float f32x4 __attribute__((ext_vector_type(4)));

// ---- x (NCHW fp32) -> xt (NHWC bf16), LDS-tiled transpose ----
__global__ __launch_bounds__(256) void nhwc_kernel(const float* __restrict__ x,
                                                   bf16_t* __restrict__ xt) {
    __shared__ float tile[64 * 65];
    const int t  = threadIdx.x;
    const int b  = blockIdx.x >> 8;
    const int p0 = (blockIdx.x & 255) << 6;
#pragma unroll
    for (int i = 0; i < 16; ++i) {
        int c = i * 4 + (t >> 6);
        int p = t & 63;
        tile[c * 65 + p] = x[(b * CC + c) * HW + p0 + p];  // coalesced read
    }
    __syncthreads();
#pragma unroll
    for (int i = 0; i < 16; ++i) {
        int p = i * 4 + (t >> 6);
        int c = t & 63;
        xt[(size_t)((b * HW) + p0 + p) * CC + c] = (bf16_t)tile[c * 65 + p];
    }
}

// ---- weight [O][C][3][3] fp32 -> B-fragment order bf16 ----
// wf element index: ((tap*2+q)*4+nt)*64*8 + lane*8 + j
//   holds W[o = nt*16 + (lane&15)][c = q*32 + (lane>>4)*8 + j][tap]
__global__ void wfrag_kernel(const float* __restrict__ w,
                             bf16_t* __restrict__ wf) {
    int i = blockIdx.x * blockDim.x + threadIdx.x;
    if (i >= OO * CC * KK) return;
    int j    = i & 7;
    int lane = (i >> 3) & 63;
    int nt   = (i >> 9) & 3;
    int q    = (i >> 11) & 1;
    int k    = i >> 12;
    int o = nt * 16 + (lane & 15);
    int c = q * 32 + ((lane >> 4) << 3) + j;
    wf[i] = (bf16_t)w[(o * CC + c) * KK + k];
}

__global__ __launch_bounds__(256, 4) void deform_conv_mfma(
    const bf16_t* __restrict__ xt, const float* __restrict__ offset,
    const float* __restrict__ mask, const bf16x8* __restrict__ wf,
    const float* __restrict__ bias, float* __restrict__ out) {
    const int t     = threadIdx.x;
    const int lane  = t & 63;
    const int wv    = t >> 6;
    const int strip = wv & 1;                  // which 16-pixel strip
    const int half  = wv >> 1;                 // which 32-channel half
    const int b     = blockIdx.x >> 9;         // 512 blocks per image
    const int p0    = (blockIdx.x & 511) << 5; // block's 32-pixel group
    const int m0    = strip << 4;
    const int col   = lane & 15;
    const int quad  = lane >> 4;

    // This lane samples pixel (p0+m0+col), channels half*32 + quad*8 .. +8
    // -- exactly its A-fragment slots for K-chunk `half`.
    const int rem = p0 + m0 + col;
    const int ho  = rem >> 7;
    const int wo  = rem & (WW - 1);
    const int cb  = (half << 5) + (quad << 3);

    const bf16_t* xb = xt + (size_t)b * HW * CC;

    __shared__ f32x4 red[2][4][64];            // [strip][nt][lane], 8 KB

    f32x4 acc[4];
#pragma unroll
    for (int nt = 0; nt < 4; ++nt) acc[nt] = (f32x4){0.f, 0.f, 0.f, 0.f};

    const int offbase = (b * (2 * KK)) * HW + rem;
    const int mbase   = (b * KK) * HW + rem;
    float offy = offset[offbase];
    float offx = offset[offbase + HW];
    float mm   = mask[mbase];

    for (int k = 0; k < KK; ++k) {
        float py = offy + (float)(k / KHW) + (float)(ho - 1);
        float px = offx + (float)(k % KHW) + (float)(wo - 1);
        float fy0 = floorf(py), fx0 = floorf(px);
        float ly = py - fy0, lx = px - fx0;
        int y0 = (int)fy0, x0 = (int)fx0;
        int y1 = y0 + 1, x1 = x0 + 1;
        bool vy0 = (y0 >= 0) && (y0 < HH);
        bool vy1 = (y1 >= 0) && (y1 < HH);
        bool vx0 = (x0 >= 0) && (x0 < WW);
        bool vx1 = (x1 >= 0) && (x1 < WW);
        int cy0 = min(max(y0, 0), HH - 1), cy1 = min(max(y1, 0), HH - 1);
        int cx0 = min(max(x0, 0), WW - 1), cx1 = min(max(x1, 0), WW - 1);
        float w0 = (vy0 && vx0) ? mm * (1.0f - ly) * (1.0f - lx) : 0.0f;
        float w1 = (vy0 && vx1) ? mm * (1.0f - ly) * lx : 0.0f;
        float w2 = (vy1 && vx0) ? mm * ly * (1.0f - lx) : 0.0f;
        float w3 = (vy1 && vx1) ? mm * ly * lx : 0.0f;

        // 4 corner loads, 16B each (lanes of a quad cover 64 contiguous B).
        bf16x8 a0 = *(const bf16x8*)(xb + (cy0 * WW + cx0) * CC + cb);
        bf16x8 a1 = *(const bf16x8*)(xb + (cy0 * WW + cx1) * CC + cb);
        bf16x8 a2 = *(const bf16x8*)(xb + (cy1 * WW + cx0) * CC + cb);
        bf16x8 a3 = *(const bf16x8*)(xb + (cy1 * WW + cx1) * CC + cb);

        // Prefetch next tap's offset/mask while corners are in flight.
        float offy_n = 0.f, offx_n = 0.f, mm_n = 0.f;
        if (k + 1 < KK) {
            offy_n = offset[offbase + (2 * k + 2) * HW];
            offx_n = offset[offbase + (2 * k + 3) * HW];
            mm_n   = mask[mbase + (k + 1) * HW];
        }

        bf16x8 af;
#pragma unroll
        for (int i = 0; i < 8; ++i) {
            float v = w0 * (float)a0[i] + w1 * (float)a1[i] +
                      w2 * (float)a2[i] + w3 * (float)a3[i];
            af[i] = (bf16_t)v;
        }

        const bf16x8* wk = wf + (size_t)((k * 2 + half) * 4) * 64;
#pragma unroll
        for (int nt = 0; nt < 4; ++nt) {
            bf16x8 bfr = wk[nt * 64 + lane];
            acc[nt] = __builtin_amdgcn_mfma_f32_16x16x32_bf16(af, bfr, acc[nt],
                                                              0, 0, 0);
        }

        offy = offy_n; offx = offx_n; mm = mm_n;
    }

    // ---- combine channel-halves, then epilogue from half==0 waves ----
    if (half == 1) {
#pragma unroll
        for (int nt = 0; nt < 4; ++nt) red[strip][nt][lane] = acc[nt];
    }
    __syncthreads();
    if (half == 0) {
#pragma unroll
        for (int nt = 0; nt < 4; ++nt) {
            int o = nt * 16 + col;
            float bv = bias[o];
            f32x4 r = acc[nt] + red[strip][nt][lane];
            r.x += bv; r.y += bv; r.z += bv; r.w += bv;
            // D[row=quad*4+reg][col]; row -> pixel, col -> output channel.
            float* dst = out + (size_t)(b * OO + o) * HW + p0 + m0 + quad * 4;
            *(f32x4*)dst = r;  // 4 consecutive pixels, 16B aligned
        }
    }
}

extern "C" void kernel_launch(void* const* d_in, const int* in_sizes, int n_in,
                              void* d_out, int out_size, void* d_ws,
                              size_t ws_size, hipStream_t stream) {
    const float* x      = (const float*)d_in[0];
    const float* offset = (const float*)d_in[1];
    const float* mask   = (const float*)d_in[2];
    const float* weight = (const float*)d_in[3];
    const float* bias   = (const float*)d_in[4];
    float* out = (float*)d_out;

    bf16_t* xt  = (bf16_t*)d_ws;                      // 4*16384*64*2 = 8 MB
    bf16_t* wfr = (bf16_t*)((char*)d_ws + (size_t)BB * HW * CC * 2);  // 72 KB

    nhwc_kernel<<<BB * (HW / 64), 256, 0, stream>>>(x, xt);

    int nw = OO * CC * KK;  // 36864
    wfrag_kernel<<<(nw + 255) / 256, 256, 0, stream>>>(weight, wfr);

    deform_conv_mfma<<<BB * (HW / 32), 256, 0, stream>>>(
        xt, offset, mask, (const bf16x8*)wfr, bias, out);
}